// Round 12
// baseline (320.006 us; speedup 1.0000x reference)
//
#include <hip/hip_runtime.h>
#include <stdint.h>

#define BATCH 8
#define SEQ   1025
#define HDIM  1152
#define NH    12
#define DH    96
#define MROWS (BATCH*SEQ)   // 8200
#define N_QKV (3*HDIM)      // 3456
#define KD    HDIM          // 1152 (K of both GEMMs)
#define NT2   18            // K-tiles of 64

typedef __attribute__((ext_vector_type(8))) short short8;
typedef __attribute__((ext_vector_type(4))) short short4_;
typedef __attribute__((ext_vector_type(4))) float float4_;
typedef __attribute__((ext_vector_type(16))) float f32x16;

#define AS1 __attribute__((address_space(1)))
#define AS3 __attribute__((address_space(3)))
#define BARM() do { asm volatile("" ::: "memory"); __builtin_amdgcn_s_barrier(); asm volatile("" ::: "memory"); } while (0)
#define LGKM0() do { asm volatile("s_waitcnt lgkmcnt(0)" ::: "memory"); __builtin_amdgcn_sched_barrier(0); } while (0)

__device__ inline float bf2f(short s) {
  union { unsigned u; float f; } x; x.u = ((unsigned)(unsigned short)s) << 16; return x.f;
}
__device__ inline short f2bf(float f) {
  union { float f; unsigned u; } x; x.f = f;
  unsigned r = (x.u + 0x7fffu + ((x.u >> 16) & 1u)) >> 16;
  return (short)r;
}

// ---------------- converts ----------------
__global__ __launch_bounds__(256) void convx(const float* __restrict__ hs, short* __restrict__ X) {
  int i = blockIdx.x * 256 + threadIdx.x;  // exactly 2361600 threads
  float4_ v = ((const float4_*)hs)[i];
  short4_ o;
  o[0] = f2bf(v[0]); o[1] = f2bf(v[1]); o[2] = f2bf(v[2]); o[3] = f2bf(v[3]);
  ((short4_*)X)[i] = o;
}

// tiled transpose-cast: Wt[z*1152 + n][k] = W_z[k][n]
__global__ __launch_bounds__(256) void convw_t(const float* __restrict__ W0,
                                               const float* __restrict__ W1,
                                               const float* __restrict__ W2,
                                               short* __restrict__ Wt) {
  __shared__ float T[64][65];
  const int z = blockIdx.z;
  const float* W = z == 0 ? W0 : (z == 1 ? W1 : W2);
  const int n0 = blockIdx.x * 64, k0 = blockIdx.y * 64;
  const int tid = threadIdx.x;
  const int r = tid >> 2, cq = (tid & 3) * 16;
#pragma unroll
  for (int u = 0; u < 4; ++u) {
    float4_ v = *(const float4_*)&W[(long)(k0 + r) * HDIM + n0 + cq + u * 4];
    T[r][cq + u * 4 + 0] = v[0]; T[r][cq + u * 4 + 1] = v[1];
    T[r][cq + u * 4 + 2] = v[2]; T[r][cq + u * 4 + 3] = v[3];
  }
  __syncthreads();
  const int n = tid >> 2, kq = (tid & 3) * 16;
  short out[16];
#pragma unroll
  for (int u = 0; u < 16; ++u) out[u] = f2bf(T[kq + u][n]);
  short* dst = Wt + (long)(z * HDIM + n0 + n) * KD + k0 + kq;
  *(short8*)dst = *(short8*)&out[0];
  *(short8*)(dst + 8) = *(short8*)&out[8];
}

// ---------------- GEMM 256x256, 8-wave, BK=64, PING-PONG wave groups ----------------
// g0 = waves 0-3 (wr=0), g1 = waves 4-7 (wr=1): one wave of each group per SIMD.
// Per K-tile, 4 slots; in every slot one group does its 12 ds_reads while the other
// does its 32 MFMAs (role-split): s1: g0.R0 | g1.M1(t-1); s2: g0.M0 | g1.R0;
// s3: g0.R1 | g1.M0; s4: g0.M1 | g1.R1. LDS and matrix pipes both busy every slot.
// LDS 128KB: A (dbuf, khalf) = [256][32] bf16 (16KB) at sb*16384 + kh*8192 sh; B at +32768.
// Swizzle (round-6 verified, 0 conflicts): line = row>>1 (128B); 16B-slot = (row&1)*4+lg;
//   phys_slot = slot ^ (line&7). Staging inverse on the per-lane SOURCE (Rule 21).
// Staging: kh0(t+1) in s1, kh1(t+1) in s2 (4 loads/thread each).
// Waits (per-thread FIFO, never 0 mid-loop): end-s2 vmcnt(8) drains kh1(t)
//   [in-flight: kh1(t),kh0(t+1),kh1(t+1)=12]; end-s4 vmcnt(4) drains kh0(t+1).
// Race-audit: each group's LGKM0 (before its MFMA) drains its reads of a buffer at least
//   one barrier before any staging overwrites that buffer (checked both kh, both groups);
//   reads can't cross asm memory-clobber barriers; MFMA sinking past barriers is harmless
//   (operands in regs, reads already drained).
template<int OUTF32>
__global__ __launch_bounds__(512, 2) void gemm256(
    const short* __restrict__ A, const short* __restrict__ Bt,
    const float* __restrict__ b0, const float* __restrict__ b1, const float* __restrict__ b2,
    void* __restrict__ Cout, const int N, const int MT) {
  __shared__ alignas(16) short Lds[65536];  // 128KB
  const int tid = threadIdx.x;
  const int l = tid & 63, w = tid >> 6;
  const int lrow = l & 15, lg = l >> 4;
  const int wr = w >> 2, wc = w & 3;
  const bool isA = (wr == 0);

  // bijective XCD swizzle (m204)
  const int nwg = gridDim.x;
  const int qq = nwg >> 3, r8 = nwg & 7;
  const int xcd = blockIdx.x & 7, loc = blockIdx.x >> 3;
  const int wg = (xcd < r8 ? xcd * (qq + 1) : r8 * (qq + 1) + (xcd - r8) * qq) + loc;
  const int mt = wg % MT, nt = wg / MT;
  const int m0 = mt * 256, n0 = nt * 256;

  // staging sources (inverse swizzle)
  const short* asrc[2]; const short* bsrc[2];
#pragma unroll
  for (int i = 0; i < 2; ++i) {
    int p = i * 512 + tid;
    int wl = (p & 7) ^ ((p >> 3) & 7);
    int row = ((p >> 3) << 1) | (wl >> 2);
    int kc = (wl & 3) * 8;
    int ra = m0 + row; if (ra > MROWS - 1) ra = MROWS - 1;
    int rb = n0 + row; if (rb > N - 1) rb = N - 1;
    asrc[i] = A + (long)ra * KD + kc;
    bsrc[i] = Bt + (long)rb * KD + kc;
  }

#define STAGEA(sb, kh, kt_, i) \
  __builtin_amdgcn_global_load_lds((const AS1 void*)(asrc[i] + (kt_) * 64 + (kh) * 32), \
      (AS3 void*)(&Lds[(sb) * 16384 + (kh) * 8192 + (i * 512 + tid) * 8]), 16, 0, 0)
#define STAGEB(sb, kh, kt_, i) \
  __builtin_amdgcn_global_load_lds((const AS1 void*)(bsrc[i] + (kt_) * 64 + (kh) * 32), \
      (AS3 void*)(&Lds[32768 + (sb) * 16384 + (kh) * 8192 + (i * 512 + tid) * 8]), 16, 0, 0)
#define STAGE_KH(sb, kh, kt_) do { \
  STAGEA(sb, kh, kt_, 0); STAGEA(sb, kh, kt_, 1); \
  STAGEB(sb, kh, kt_, 0); STAGEB(sb, kh, kt_, 1); } while (0)
#define LDA(dst, base, mi) { const int row_ = wr * 128 + (mi) * 16 + lrow; \
  dst = *(const short8*)&Lds[(base) + ((row_ >> 1) << 6) + \
      (((((row_ & 1) << 2) + lg) ^ ((row_ >> 1) & 7)) << 3)]; }
#define LDB(dst, base, nj) { const int row_ = wc * 64 + (nj) * 16 + lrow; \
  dst = *(const short8*)&Lds[(base) + ((row_ >> 1) << 6) + \
      (((((row_ & 1) << 2) + lg) ^ ((row_ >> 1) & 7)) << 3)]; }
#define RD(aB, bB) do { \
  LDB(bf0, bB, 0); LDB(bf1, bB, 1); LDB(bf2, bB, 2); LDB(bf3, bB, 3); \
  LDA(af0, aB, 0); LDA(af1, aB, 1); LDA(af2, aB, 2); LDA(af3, aB, 3); \
  LDA(af4, aB, 4); LDA(af5, aB, 5); LDA(af6, aB, 6); LDA(af7, aB, 7); } while (0)
#define MFMA16(a, b, c) __builtin_amdgcn_mfma_f32_16x16x32_bf16(a, b, c, 0, 0, 0)
#define MF16(mb, A0, A1, A2, A3) \
  acc[(mb)+0][0] = MFMA16(A0, bf0, acc[(mb)+0][0]); \
  acc[(mb)+0][1] = MFMA16(A0, bf1, acc[(mb)+0][1]); \
  acc[(mb)+0][2] = MFMA16(A0, bf2, acc[(mb)+0][2]); \
  acc[(mb)+0][3] = MFMA16(A0, bf3, acc[(mb)+0][3]); \
  acc[(mb)+1][0] = MFMA16(A1, bf0, acc[(mb)+1][0]); \
  acc[(mb)+1][1] = MFMA16(A1, bf1, acc[(mb)+1][1]); \
  acc[(mb)+1][2] = MFMA16(A1, bf2, acc[(mb)+1][2]); \
  acc[(mb)+1][3] = MFMA16(A1, bf3, acc[(mb)+1][3]); \
  acc[(mb)+2][0] = MFMA16(A2, bf0, acc[(mb)+2][0]); \
  acc[(mb)+2][1] = MFMA16(A2, bf1, acc[(mb)+2][1]); \
  acc[(mb)+2][2] = MFMA16(A2, bf2, acc[(mb)+2][2]); \
  acc[(mb)+2][3] = MFMA16(A2, bf3, acc[(mb)+2][3]); \
  acc[(mb)+3][0] = MFMA16(A3, bf0, acc[(mb)+3][0]); \
  acc[(mb)+3][1] = MFMA16(A3, bf1, acc[(mb)+3][1]); \
  acc[(mb)+3][2] = MFMA16(A3, bf2, acc[(mb)+3][2]); \
  acc[(mb)+3][3] = MFMA16(A3, bf3, acc[(mb)+3][3]);
#define MF32() do { \
  __builtin_amdgcn_s_setprio(1); \
  MF16(0, af0, af1, af2, af3); \
  MF16(4, af4, af5, af6, af7); \
  __builtin_amdgcn_s_setprio(0); } while (0)

  float4_ acc[8][4];
#pragma unroll
  for (int mi = 0; mi < 8; ++mi)
#pragma unroll
    for (int nj = 0; nj < 4; ++nj) acc[mi][nj] = (float4_)(0.f);
  short8 af0, af1, af2, af3, af4, af5, af6, af7, bf0, bf1, bf2, bf3;

  // prologue: stage tile 0 (kh0 then kh1) into buf 0
  STAGE_KH(0, 0, 0);
  STAGE_KH(0, 1, 0);
  asm volatile("s_waitcnt vmcnt(4)" ::: "memory");   // kh0(0) landed (oldest 4)
  BARM();

  for (int kt = 0; kt < NT2; ++kt) {
    const int cb = kt & 1, sbuf = cb ^ 1;
    const bool dost = (kt + 1) < NT2;
    const int aK0 = cb * 16384, aK1 = aK0 + 8192;
    const int bK0 = 32768 + cb * 16384, bK1 = bK0 + 8192;

    // ---- slot 1: stage kh0(kt+1); g0 reads kh0(kt); g1 MFMAs kh1(kt-1) ----
    if (dost) STAGE_KH(sbuf, 0, kt + 1);
    if (isA) { RD(aK0, bK0); }
    else if (kt > 0) { LGKM0(); MF32(); }
    BARM();
    // ---- slot 2: stage kh1(kt+1); g0 MFMA kh0; g1 reads kh0 ----
    if (dost) STAGE_KH(sbuf, 1, kt + 1);
    if (isA) { LGKM0(); MF32(); }
    else { RD(aK0, bK0); }
    if (dost) asm volatile("s_waitcnt vmcnt(8)" ::: "memory");  // kh1(kt) landed
    else      asm volatile("s_waitcnt vmcnt(0)" ::: "memory");  // tail drain
    BARM();
    // ---- slot 3: g0 reads kh1; g1 MFMA kh0 ----
    if (isA) { RD(aK1, bK1); }
    else { LGKM0(); MF32(); }
    BARM();
    // ---- slot 4: g0 MFMA kh1; g1 reads kh1 ----
    if (isA) { LGKM0(); MF32(); }
    else { RD(aK1, bK1); }
    if (dost) asm volatile("s_waitcnt vmcnt(4)" ::: "memory");  // kh0(kt+1) landed
    BARM();
  }
  // epilogue slot: g1's pending MFMA on kh1(last)
  if (!isA) { LGKM0(); MF32(); }

  // epilogue: 16x16 C layout row = lg*4 + r, col = lrow
  float bias[4];
#pragma unroll
  for (int nj = 0; nj < 4; ++nj) {
    int cn = n0 + wc * 64 + nj * 16 + lrow;
    float bv_ = 0.f;
    if (cn < N) bv_ = (N == HDIM) ? b0[cn]
                                  : (cn < HDIM ? b0[cn] : (cn < 2 * HDIM ? b1[cn - HDIM] : b2[cn - 2 * HDIM]));
    bias[nj] = bv_;
  }
#pragma unroll
  for (int mi = 0; mi < 8; ++mi)
#pragma unroll
    for (int r = 0; r < 4; ++r) {
      int m = m0 + wr * 128 + mi * 16 + lg * 4 + r;
      if (m >= MROWS) continue;
#pragma unroll
      for (int nj = 0; nj < 4; ++nj) {
        int cn = n0 + wc * 64 + nj * 16 + lrow;
        if (cn >= N) continue;
        float v = acc[mi][nj][r] + bias[nj];
        if (OUTF32) ((float*)Cout)[(long)m * N + cn] = v;
        else        ((short*)Cout)[(long)m * N + cn] = f2bf(v);
      }
    }
#undef STAGEA
#undef STAGEB
#undef STAGE_KH
#undef LDA
#undef LDB
#undef RD
#undef MFMA16
#undef MF16
#undef MF32
}

// ---------------- rotary on Q only (vectorized short8; K handled in fragpack) ----------------
__global__ __launch_bounds__(256) void rotary_q(short* __restrict__ QKV,
                                                const int* __restrict__ rowsp,
                                                const int* __restrict__ colsp) {
  int idx = blockIdx.x * 256 + threadIdx.x;
  if (idx >= MROWS * NH * 4) return;
  const int qt = idx & 3;
  const int hm = idx >> 2;
  const int h = hm % NH, m = hm / NH;
  const int s = m % SEQ;
  const int cols = colsp[0], rws = rowsp[0];
  const int off = (SEQ != rws * cols) ? 1 : 0;
  int gid = s - off; if (gid < 0) gid = 0;
  const float frow = (float)(gid / cols), fcol = (float)(gid % cols);
  union { short sh[24]; short8 v[3]; } u;
  short* p = QKV + (long)m * N_QKV + h * DH + qt * 24;
  u.v[0] = *(short8*)p; u.v[1] = *(short8*)(p + 8); u.v[2] = *(short8*)(p + 16);
#pragma unroll
  for (int t = 0; t < 8; ++t) {
    int j = qt * 8 + t;
    float invf = exp2f((float)(3 * j) * (-13.287712379549449f / 192.0f));
    float st, ct, sp, cp;
    __sincosf(frow * invf, &st, &ct);
    __sincosf(fcol * invf, &sp, &cp);
    float x0 = bf2f(u.sh[3 * t]), x1 = bf2f(u.sh[3 * t + 1]), x2 = bf2f(u.sh[3 * t + 2]);
    u.sh[3 * t]     = f2bf( cp * x0 + sp * st * x1 + sp * ct * x2);
    u.sh[3 * t + 1] = f2bf( ct * x1 - st * x2);
    u.sh[3 * t + 2] = f2bf(-sp * x0 + cp * st * x1 + cp * ct * x2);
  }
  *(short8*)p = u.v[0]; *(short8*)(p + 8) = u.v[1]; *(short8*)(p + 16) = u.v[2];
}

// ---------------- fragment prepack (+K rotary fused) ----------------
__global__ __launch_bounds__(256) void fragpack(const short* __restrict__ QKV,
                                                short* __restrict__ Kf,
                                                short* __restrict__ Vf,
                                                const int* __restrict__ rowsp,
                                                const int* __restrict__ colsp) {
  __shared__ short L[64 * 96];  // [kv=2][row 32][96]
  const int t = blockIdx.x, bh = blockIdx.y;
  const int b = bh / NH, h = bh % NH;
  const int tid = threadIdx.x;
#pragma unroll
  for (int i = 0; i < 3; ++i) {
    int cc = i * 256 + tid;
    int kv = cc / 384;
    int rm = cc % 384;
    int r = rm / 12, m = rm % 12;
    int s = t * 32 + r; if (s > SEQ - 1) s = SEQ - 1;
    const short* src = QKV + (long)(b * SEQ + s) * N_QKV + (kv ? 2 * HDIM : HDIM) + h * DH + m * 8;
    *(short8*)&L[cc * 8] = *(const short8*)src;
  }
  __syncthreads();
  {
    const int cols = colsp[0], rws = rowsp[0];
    const int off = (SEQ != rws * cols) ? 1 : 0;
#pragma unroll
    for (int i = 0; i < 4; ++i) {
      int idx2 = i * 256 + tid;      // 1024 = 32 rows x 32 triplets
      int r = idx2 >> 5, j = idx2 & 31;
      int s = t * 32 + r; if (s > SEQ - 1) s = SEQ - 1;
      int gid = s - off; if (gid < 0) gid = 0;
      float invf = exp2f((float)(3 * j) * (-13.287712379549449f / 192.0f));
      float st, ct, sp, cp;
      __sincosf((float)(gid / cols) * invf, &st, &ct);
      __sincosf((float)(gid % cols) * invf, &sp, &cp);
      short* pp = &L[r * 96 + 3 * j];
      float x0 = bf2f(pp[0]), x1 = bf2f(pp[1]), x2 = bf2f(pp[2]);
      pp[0] = f2bf( cp * x0 + sp * st * x1 + sp * ct * x2);
      pp[1] = f2bf( ct * x1 - st * x2);
      pp[2] = f2bf(-sp * x0 + cp * st * x1 + cp * ct * x2);
    }
  }
  __syncthreads();
#pragma unroll
  for (int i = 0; i < 3; ++i) {
    int oc = i * 256 + tid;
    if (oc < 384) {
      int c = oc / 64, ll = oc & 63;
      int qi = ll & 31, hi = ll >> 5;
      short8 v = *(const short8*)&L[qi * 96 + c * 16 + hi * 8];
      *(short8*)(Kf + (((long)(bh * 33 + t) * 6 + c) * 64 + ll) * 8) = v;
    } else {
      int oc2 = oc - 384;
      int d = oc2 / 128, sl = (oc2 / 64) & 1, ll = oc2 & 63;
      int qi = ll & 31, hi = ll >> 5;
      short8 v;
#pragma unroll
      for (int j = 0; j < 8; ++j)
        v[j] = L[32 * 96 + (sl * 16 + hi * 8 + j) * 96 + d * 32 + qi];
      *(short8*)(Vf + ((((long)(bh * 33 + t) * 3 + d) * 2 + sl) * 64 + ll) * 8) = v;
    }
  }
}

// ---------------- flash attention, swapped-operand 32x32, prepacked K/V ----------------
__global__ __launch_bounds__(128, 3) void attn_kernel(const short* __restrict__ QKV,
                                                      const short* __restrict__ Kf,
                                                      const short* __restrict__ Vf,
                                                      short* __restrict__ CTX) {
  const int tid = threadIdx.x;
  const int l = tid & 63, w = tid >> 6;
  const int qi = l & 31, hi = l >> 5;
  const int bid = blockIdx.x;
  const int xcd = bid & 7, jj = bid >> 3;
  const int bh = xcd * 12 + jj / 17;
  const int qb = jj % 17;
  const int b = bh / NH, h = bh % NH;
  const int s = qb * 64 + w * 32 + qi;
  const int sq = s > SEQ - 1 ? SEQ - 1 : s;

  const float scale = 0.1020620726159658f;  // 96^-0.5
  const short* Qr = QKV + (long)(b * SEQ + sq) * N_QKV + h * DH;
  short8 qf[6];
#pragma unroll
  for (int c = 0; c < 6; ++c) {
    short8 v = *(const short8*)(Qr + c * 16 + hi * 8);
#pragma unroll
    for (int j = 0; j < 8; ++j) v[j] = f2bf(bf2f(v[j]) * scale);
    qf[c] = v;
  }

  const short* Kb = Kf + (long)bh * 33 * 6 * 64 * 8;
  const short* Vb = Vf + (long)bh * 33 * 6 * 64 * 8;

  f32x16 ctxv[3];
#pragma unroll
  for (int d = 0; d < 3; ++d) ctxv[d] = (f32x16)(0.f);
  float m_ = -1e30f, l_ = 0.f;

  for (int t = 0; t < 33; ++t) {
    f32x16 S = (f32x16)(0.f);
#pragma unroll
    for (int c = 0; c < 6; ++c) {
      short8 kf = *(const short8*)(Kb + (((long)t * 6 + c) * 64 + l) * 8);
      S = __builtin_amdgcn_mfma_f32_32x32x16_bf16(kf, qf[c], S, 0, 0, 0);
    }
    if (t == 32) {
      S[0] = hi ? -1e30f : S[0];
#pragma unroll
      for (int r = 1; r < 16; ++r) S[r] = -1e30f;
    }
    float tm = S[0];
#pragma unroll
    for (int r = 1; r < 16; ++r) tm = fmaxf(tm, S[r]);
    tm = fmaxf(tm, __shfl_xor(tm, 32));
    if (!__all(tm - m_ <= 8.f)) {
      float mn = fmaxf(m_, tm);
      float alpha = __expf(m_ - mn);
      m_ = mn;
      l_ *= alpha;
#pragma unroll
      for (int d = 0; d < 3; ++d)
#pragma unroll
        for (int r = 0; r < 16; ++r) ctxv[d][r] *= alpha;
    }
    float ts = 0.f;
#pragma unroll
    for (int r = 0; r < 16; ++r) { float p = __expf(S[r] - m_); S[r] = p; ts += p; }
    ts += __shfl_xor(ts, 32);
    l_ += ts;

    unsigned pk_[8];
#pragma unroll
    for (int j = 0; j < 8; ++j)
      pk_[j] = (unsigned)(unsigned short)f2bf(S[2 * j]) |
               ((unsigned)(unsigned short)f2bf(S[2 * j + 1]) << 16);
    unsigned s0 = hi ? pk_[0] : pk_[2];
    unsigned s1 = hi ? pk_[1] : pk_[3];
    unsigned s2 = hi ? pk_[4] : pk_[6];
    unsigned s3 = hi ? pk_[5] : pk_[7];
    unsigned r0 = __shfl_xor(s0, 32);
    unsigned r1 = __shfl_xor(s1, 32);
    unsigned r2 = __shfl_xor(s2, 32);
    unsigned r3 = __shfl_xor(s3, 32);
    union PF { unsigned u[4]; short8 s8; } f0, f1;
    f0.u[0] = hi ? r0 : pk_[0];
    f0.u[1] = hi ? r1 : pk_[1];
    f0.u[2] = hi ? pk_[2] : r0;
    f0.u[3] = hi ? pk_[3] : r1;
    f1.u[0] = hi ? r2 : pk_[4];
    f1.u[1] = hi ? r3 : pk_[5];
    f1.u[2] = hi ? pk_[6] : r2;
    f1.u[3] = hi ? pk_[7] : r3;

#pragma unroll
    for (int d = 0; d < 3; ++d) {
      const short* Vr = Vb + (((long)t * 3 + d) * 2 * 64) * 8;
      short8 vf0 = *(const short8*)(Vr + l * 8);
      ctxv[d] = __builtin_amdgcn_mfma_f32_32x32x16_bf16(vf0, f0.s8, ctxv[d], 0, 0, 0);
      short8 vf1 = *(const short8*)(Vr + (64 + l) * 8);
      ctxv[d] = __builtin_amdgcn_mfma_f32_32x32x16_bf16(vf1, f1.s8, ctxv[d], 0, 0, 0);
    }
  }

  float invl = 1.f / l_;
  if (s <= SEQ - 1) {
    short* Cr = CTX + (long)(b * SEQ + s) * HDIM + h * DH;
#pragma unroll
    for (int d = 0; d < 3; ++d)
#pragma unroll
      for (int g = 0; g < 4; ++g) {
        short4_ o;
#pragma unroll
        for (int r = 0; r < 4; ++r) o[r] = f2bf(ctxv[d][4 * g + r] * invl);
        *(short4_*)(Cr + d * 32 + 8 * g + 4 * hi) = o;
      }
  }
}

extern "C" void kernel_launch(void* const* d_in, const int* in_sizes, int n_in,
                              void* d_out, int out_size, void* d_ws, size_t ws_size,
                              hipStream_t stream) {
  const float* hs = (const float*)d_in[0];
  const float* Wq = (const float*)d_in[1];
  const float* bq = (const float*)d_in[2];
  const float* Wk = (const float*)d_in[3];
  const float* bk = (const float*)d_in[4];
  const float* Wv = (const float*)d_in[5];
  const float* bv = (const float*)d_in[6];
  const float* Wo = (const float*)d_in[7];
  const float* bo = (const float*)d_in[8];
  const int* rows = (const int*)d_in[9];
  const int* cols = (const int*)d_in[10];
  float* out = (float*)d_out;

  char* ws = (char*)d_ws;
  short* X   = (short*)(ws);               // 8200*1152*2      = 18,892,800
  short* Wt  = (short*)(ws + 18892800);    // 3456*1152*2      =  7,962,624
  short* Wot = (short*)(ws + 26855424);    // 1152*1152*2      =  2,654,208
  short* QKV = (short*)(ws + 29509632);    // 8200*3456*2      = 56,678,400
  short* Vf  = (short*)(ws + 86188032);    // 96*33*6*64*16B   = 19,464,192
  short* CTX = (short*)(ws + 105652224);   // 8200*1152*2      = 18,892,800  (end 124,545,024)
  short* Kf  = (short*)(ws);               // 19,464,192 — reuses X+Wt region (dead after gemm<0>)

  convx<<<9225, 256, 0, stream>>>(hs, X);
  convw_t<<<dim3(18, 18, 3), 256, 0, stream>>>(Wq, Wk, Wv, Wt);
  convw_t<<<dim3(18, 18, 1), 256, 0, stream>>>(Wo, Wo, Wo, Wot);
  gemm256<0><<<462, 512, 0, stream>>>(X, Wt, bq, bk, bv, QKV, N_QKV, 33);   // 33 M x 14 N tiles
  rotary_q<<<1538, 256, 0, stream>>>(QKV, rows, cols);
  fragpack<<<dim3(33, 96), 256, 0, stream>>>(QKV, Kf, Vf, rows, cols);
  attn_kernel<<<1632, 128, 0, stream>>>(QKV, Kf, Vf, CTX);
  gemm256<1><<<165, 512, 0, stream>>>(CTX, Wot, bo, bo, bo, out, HDIM, 33); // 33 M x 5 N tiles
}

// Round 13
// 267.018 us; speedup vs baseline: 1.1984x; 1.1984x over previous
//
#include <hip/hip_runtime.h>
#include <stdint.h>

#define BATCH 8
#define SEQ   1025
#define HDIM  1152
#define NH    12
#define DH    96
#define MROWS (BATCH*SEQ)   // 8200
#define N_QKV (3*HDIM)      // 3456
#define KD    HDIM          // 1152 (K of both GEMMs)
#define NT2   18            // K-tiles of 64
#define NTK   36            // K-tiles of 32

typedef __attribute__((ext_vector_type(8))) short short8;
typedef __attribute__((ext_vector_type(4))) short short4_;
typedef __attribute__((ext_vector_type(4))) float float4_;
typedef __attribute__((ext_vector_type(16))) float f32x16;

#define AS1 __attribute__((address_space(1)))
#define AS3 __attribute__((address_space(3)))
#define BARM() do { asm volatile("" ::: "memory"); __builtin_amdgcn_s_barrier(); asm volatile("" ::: "memory"); } while (0)
#define LGKM0() do { asm volatile("s_waitcnt lgkmcnt(0)" ::: "memory"); __builtin_amdgcn_sched_barrier(0); } while (0)

__device__ inline float bf2f(short s) {
  union { unsigned u; float f; } x; x.u = ((unsigned)(unsigned short)s) << 16; return x.f;
}
__device__ inline short f2bf(float f) {
  union { float f; unsigned u; } x; x.f = f;
  unsigned r = (x.u + 0x7fffu + ((x.u >> 16) & 1u)) >> 16;
  return (short)r;
}

// ---------------- converts ----------------
__global__ __launch_bounds__(256) void convx(const float* __restrict__ hs, short* __restrict__ X) {
  int i = blockIdx.x * 256 + threadIdx.x;  // exactly 2361600 threads
  float4_ v = ((const float4_*)hs)[i];
  short4_ o;
  o[0] = f2bf(v[0]); o[1] = f2bf(v[1]); o[2] = f2bf(v[2]); o[3] = f2bf(v[3]);
  ((short4_*)X)[i] = o;
}

// tiled transpose-cast: Wt[z*1152 + n][k] = W_z[k][n]
__global__ __launch_bounds__(256) void convw_t(const float* __restrict__ W0,
                                               const float* __restrict__ W1,
                                               const float* __restrict__ W2,
                                               short* __restrict__ Wt) {
  __shared__ float T[64][65];
  const int z = blockIdx.z;
  const float* W = z == 0 ? W0 : (z == 1 ? W1 : W2);
  const int n0 = blockIdx.x * 64, k0 = blockIdx.y * 64;
  const int tid = threadIdx.x;
  const int r = tid >> 2, cq = (tid & 3) * 16;
#pragma unroll
  for (int u = 0; u < 4; ++u) {
    float4_ v = *(const float4_*)&W[(long)(k0 + r) * HDIM + n0 + cq + u * 4];
    T[r][cq + u * 4 + 0] = v[0]; T[r][cq + u * 4 + 1] = v[1];
    T[r][cq + u * 4 + 2] = v[2]; T[r][cq + u * 4 + 3] = v[3];
  }
  __syncthreads();
  const int n = tid >> 2, kq = (tid & 3) * 16;
  short out[16];
#pragma unroll
  for (int u = 0; u < 16; ++u) out[u] = f2bf(T[kq + u][n]);
  short* dst = Wt + (long)(z * HDIM + n0 + n) * KD + k0 + kq;
  *(short8*)dst = *(short8*)&out[0];
  *(short8*)(dst + 8) = *(short8*)&out[8];
}

// ---------------- GEMM 256x256 (round-11 best, verified): 8-wave, BK=64, 4-phase ----------------
template<int OUTF32>
__global__ __launch_bounds__(512, 2) void gemm256(
    const short* __restrict__ A, const short* __restrict__ Bt,
    const float* __restrict__ b0, const float* __restrict__ b1, const float* __restrict__ b2,
    void* __restrict__ Cout, const int N, const int MT) {
  __shared__ alignas(16) short Lds[65536];  // 128KB
  const int tid = threadIdx.x;
  const int l = tid & 63, w = tid >> 6;
  const int lrow = l & 15, lg = l >> 4;
  const int wr = w >> 2, wc = w & 3;

  // bijective XCD swizzle (m204)
  const int nwg = gridDim.x;
  const int qq = nwg >> 3, r8 = nwg & 7;
  const int xcd = blockIdx.x & 7, loc = blockIdx.x >> 3;
  const int wg = (xcd < r8 ? xcd * (qq + 1) : r8 * (qq + 1) + (xcd - r8) * qq) + loc;
  const int mt = wg % MT, nt = wg / MT;
  const int m0 = mt * 256, n0 = nt * 256;

  // staging sources (inverse swizzle, round-6 verified: 0 conflicts)
  const short* asrc[2]; const short* bsrc[2];
#pragma unroll
  for (int i = 0; i < 2; ++i) {
    int p = i * 512 + tid;
    int wl = (p & 7) ^ ((p >> 3) & 7);
    int row = ((p >> 3) << 1) | (wl >> 2);
    int kc = (wl & 3) * 8;
    int ra = m0 + row; if (ra > MROWS - 1) ra = MROWS - 1;
    int rb = n0 + row; if (rb > N - 1) rb = N - 1;
    asrc[i] = A + (long)ra * KD + kc;
    bsrc[i] = Bt + (long)rb * KD + kc;
  }

#define STAGEA(sb, kh, kt_, i) \
  __builtin_amdgcn_global_load_lds((const AS1 void*)(asrc[i] + (kt_) * 64 + (kh) * 32), \
      (AS3 void*)(&Lds[(sb) * 16384 + (kh) * 8192 + (i * 512 + tid) * 8]), 16, 0, 0)
#define STAGEB(sb, kh, kt_, i) \
  __builtin_amdgcn_global_load_lds((const AS1 void*)(bsrc[i] + (kt_) * 64 + (kh) * 32), \
      (AS3 void*)(&Lds[32768 + (sb) * 16384 + (kh) * 8192 + (i * 512 + tid) * 8]), 16, 0, 0)
#define LDA(dst, base, mi) { const int row_ = wr * 128 + (mi) * 16 + lrow; \
  dst = *(const short8*)&Lds[(base) + ((row_ >> 1) << 6) + \
      (((((row_ & 1) << 2) + lg) ^ ((row_ >> 1) & 7)) << 3)]; }
#define LDB(dst, base, nj) { const int row_ = wc * 64 + (nj) * 16 + lrow; \
  dst = *(const short8*)&Lds[(base) + ((row_ >> 1) << 6) + \
      (((((row_ & 1) << 2) + lg) ^ ((row_ >> 1) & 7)) << 3)]; }
#define MFMA16(a, b, c) __builtin_amdgcn_mfma_f32_16x16x32_bf16(a, b, c, 0, 0, 0)
#define MF16(mb, A0, A1, A2, A3) \
  acc[(mb)+0][0] = MFMA16(A0, bf0, acc[(mb)+0][0]); \
  acc[(mb)+0][1] = MFMA16(A0, bf1, acc[(mb)+0][1]); \
  acc[(mb)+0][2] = MFMA16(A0, bf2, acc[(mb)+0][2]); \
  acc[(mb)+0][3] = MFMA16(A0, bf3, acc[(mb)+0][3]); \
  acc[(mb)+1][0] = MFMA16(A1, bf0, acc[(mb)+1][0]); \
  acc[(mb)+1][1] = MFMA16(A1, bf1, acc[(mb)+1][1]); \
  acc[(mb)+1][2] = MFMA16(A1, bf2, acc[(mb)+1][2]); \
  acc[(mb)+1][3] = MFMA16(A1, bf3, acc[(mb)+1][3]); \
  acc[(mb)+2][0] = MFMA16(A2, bf0, acc[(mb)+2][0]); \
  acc[(mb)+2][1] = MFMA16(A2, bf1, acc[(mb)+2][1]); \
  acc[(mb)+2][2] = MFMA16(A2, bf2, acc[(mb)+2][2]); \
  acc[(mb)+2][3] = MFMA16(A2, bf3, acc[(mb)+2][3]); \
  acc[(mb)+3][0] = MFMA16(A3, bf0, acc[(mb)+3][0]); \
  acc[(mb)+3][1] = MFMA16(A3, bf1, acc[(mb)+3][1]); \
  acc[(mb)+3][2] = MFMA16(A3, bf2, acc[(mb)+3][2]); \
  acc[(mb)+3][3] = MFMA16(A3, bf3, acc[(mb)+3][3]);

  float4_ acc[8][4];
#pragma unroll
  for (int mi = 0; mi < 8; ++mi)
#pragma unroll
    for (int nj = 0; nj < 4; ++nj) acc[mi][nj] = (float4_)(0.f);

  // prologue: stage tile 0 in FIFO order A-kh0, B-kh0, A-kh1, B-kh1 (8 loads)
  STAGEA(0, 0, 0, 0); STAGEA(0, 0, 0, 1);
  STAGEB(0, 0, 0, 0); STAGEB(0, 0, 0, 1);
  STAGEA(0, 1, 0, 0); STAGEA(0, 1, 0, 1);
  STAGEB(0, 1, 0, 0); STAGEB(0, 1, 0, 1);
  asm volatile("s_waitcnt vmcnt(4)" ::: "memory");   // tile-0 kh0 landed (oldest 4)
  BARM();

  for (int kt = 0; kt < NT2; ++kt) {
    const int cb = kt & 1, sb = (kt + 1) & 1;
    const bool dost = (kt + 1) < NT2;
    const int aK0 = cb * 16384, aK1 = aK0 + 8192;
    const int bK0 = 32768 + cb * 16384, bK1 = bK0 + 8192;
    short8 af0, af1, af2, af3, bf0, bf1, bf2, bf3;

    // ---- phase 1 (kh0, mh0): 12 ds_reads; stage A-kh0(kt+1) ----
    LDB(bf0, bK0, 0); LDB(bf1, bK0, 1); LDB(bf2, bK0, 2); LDB(bf3, bK0, 3);
    LDA(af0, aK0, 0); LDA(af1, aK0, 1); LDA(af2, aK0, 2); LDA(af3, aK0, 3);
    if (dost) { STAGEA(sb, 0, kt + 1, 0); STAGEA(sb, 0, kt + 1, 1); }
    BARM();
    LGKM0();
    __builtin_amdgcn_s_setprio(1);
    MF16(0, af0, af1, af2, af3);
    __builtin_amdgcn_s_setprio(0);
    BARM();
    // ---- phase 2 (kh0, mh1): 4 ds_reads; stage B-kh0(kt+1); mid counted vmcnt ----
    LDA(af0, aK0, 4); LDA(af1, aK0, 5); LDA(af2, aK0, 6); LDA(af3, aK0, 7);
    if (dost) { STAGEB(sb, 0, kt + 1, 0); STAGEB(sb, 0, kt + 1, 1); }
    BARM();
    LGKM0();
    __builtin_amdgcn_s_setprio(1);
    MF16(4, af0, af1, af2, af3);
    __builtin_amdgcn_s_setprio(0);
    if (dost) asm volatile("s_waitcnt vmcnt(4)" ::: "memory");  // kt's kh1 landed
    else      asm volatile("s_waitcnt vmcnt(0)" ::: "memory");  // tail drain
    BARM();
    // ---- phase 3 (kh1, mh0): 12 ds_reads; stage A-kh1(kt+1) ----
    LDB(bf0, bK1, 0); LDB(bf1, bK1, 1); LDB(bf2, bK1, 2); LDB(bf3, bK1, 3);
    LDA(af0, aK1, 0); LDA(af1, aK1, 1); LDA(af2, aK1, 2); LDA(af3, aK1, 3);
    if (dost) { STAGEA(sb, 1, kt + 1, 0); STAGEA(sb, 1, kt + 1, 1); }
    BARM();
    LGKM0();
    __builtin_amdgcn_s_setprio(1);
    MF16(0, af0, af1, af2, af3);
    __builtin_amdgcn_s_setprio(0);
    BARM();
    // ---- phase 4 (kh1, mh1): 4 ds_reads; stage B-kh1(kt+1); boundary counted vmcnt ----
    LDA(af0, aK1, 4); LDA(af1, aK1, 5); LDA(af2, aK1, 6); LDA(af3, aK1, 7);
    if (dost) { STAGEB(sb, 1, kt + 1, 0); STAGEB(sb, 1, kt + 1, 1); }
    BARM();
    LGKM0();
    __builtin_amdgcn_s_setprio(1);
    MF16(4, af0, af1, af2, af3);
    __builtin_amdgcn_s_setprio(0);
    if (dost) asm volatile("s_waitcnt vmcnt(4)" ::: "memory");  // (kt+1)'s kh0 landed
    BARM();
  }

  // epilogue: 16x16 C layout row = lg*4 + r, col = lrow
  float bias[4];
#pragma unroll
  for (int nj = 0; nj < 4; ++nj) {
    int cn = n0 + wc * 64 + nj * 16 + lrow;
    float bv_ = 0.f;
    if (cn < N) bv_ = (N == HDIM) ? b0[cn]
                                  : (cn < HDIM ? b0[cn] : (cn < 2 * HDIM ? b1[cn - HDIM] : b2[cn - 2 * HDIM]));
    bias[nj] = bv_;
  }
#pragma unroll
  for (int mi = 0; mi < 8; ++mi)
#pragma unroll
    for (int r = 0; r < 4; ++r) {
      int m = m0 + wr * 128 + mi * 16 + lg * 4 + r;
      if (m >= MROWS) continue;
#pragma unroll
      for (int nj = 0; nj < 4; ++nj) {
        int cn = n0 + wc * 64 + nj * 16 + lrow;
        if (cn >= N) continue;
        float v = acc[mi][nj][r] + bias[nj];
        if (OUTF32) ((float*)Cout)[(long)m * N + cn] = v;
        else        ((short*)Cout)[(long)m * N + cn] = f2bf(v);
      }
    }
#undef STAGEA
#undef STAGEB
#undef LDA
#undef LDB
#undef MFMA16
#undef MF16
}

// ---------------- GEMM 128x128 (round-9 verified): 4-wave, triple-buffered BK=32, 3 blk/CU ----
// Used for the N=1152 out-proj where a 256^2 grid would leave 36% of CUs idle.
template<int OUTF32>
__global__ __launch_bounds__(256, 3) void gemm128(
    const short* __restrict__ A, const short* __restrict__ Bt,
    const float* __restrict__ b0,
    void* __restrict__ Cout, const int N, const int MT) {
  __shared__ alignas(16) short Lds[24576];  // 48KB
  const int tid = threadIdx.x;
  const int l = tid & 63, w = tid >> 6;
  const int lrow = l & 15, lg = l >> 4;
  const int wr = w >> 1, wc = w & 1;

  const int nwg = gridDim.x;
  const int qq = nwg >> 3, r8 = nwg & 7;
  const int xcd = blockIdx.x & 7, loc = blockIdx.x >> 3;
  const int wg = (xcd < r8 ? xcd * (qq + 1) : r8 * (qq + 1) + (xcd - r8) * qq) + loc;
  const int mt = wg % MT, nt = wg / MT;
  const int m0 = mt * 128, n0 = nt * 128;

  const short* asrc[2]; const short* bsrc[2];
#pragma unroll
  for (int i = 0; i < 2; ++i) {
    int p = i * 256 + tid;
    int wl = (p & 7) ^ ((p >> 3) & 7);
    int row = ((p >> 3) << 1) | (wl >> 2);
    int kc = (wl & 3) * 8;
    int ra = m0 + row; if (ra > MROWS - 1) ra = MROWS - 1;
    int rb = n0 + row; if (rb > N - 1) rb = N - 1;
    asrc[i] = A + (long)ra * KD + kc;
    bsrc[i] = Bt + (long)rb * KD + kc;
  }

#define STAGEA(bi, kt_, i) \
  __builtin_amdgcn_global_load_lds((const AS1 void*)(asrc[i] + (kt_) * 32), \
      (AS3 void*)(&Lds[(bi) * 4096 + (i * 256 + tid) * 8]), 16, 0, 0)
#define STAGEB(bi, kt_, i) \
  __builtin_amdgcn_global_load_lds((const AS1 void*)(bsrc[i] + (kt_) * 32), \
      (AS3 void*)(&Lds[12288 + (bi) * 4096 + (i * 256 + tid) * 8]), 16, 0, 0)
#define LDA(dst, abase, mi) { const int row_ = wr * 64 + (mi) * 16 + lrow; \
  dst = *(const short8*)&Lds[(abase) + ((row_ >> 1) << 6) + \
      (((((row_ & 1) << 2) + lg) ^ ((row_ >> 1) & 7)) << 3)]; }
#define LDB(dst, bbase, nj) { const int row_ = wc * 64 + (nj) * 16 + lrow; \
  dst = *(const short8*)&Lds[(bbase) + ((row_ >> 1) << 6) + \
      (((((row_ & 1) << 2) + lg) ^ ((row_ >> 1) & 7)) << 3)]; }
#define MFMA16(a, b, c) __builtin_amdgcn_mfma_f32_16x16x32_bf16(a, b, c, 0, 0, 0)

  float4_ acc[4][4];
#pragma unroll
  for (int mi = 0; mi < 4; ++mi)
#pragma unroll
    for (int nj = 0; nj < 4; ++nj) acc[mi][nj] = (float4_)(0.f);

  STAGEA(0, 0, 0); STAGEA(0, 0, 1); STAGEB(0, 0, 0); STAGEB(0, 0, 1);
  STAGEA(1, 1, 0); STAGEA(1, 1, 1); STAGEB(1, 1, 0); STAGEB(1, 1, 1);
  asm volatile("s_waitcnt vmcnt(4)" ::: "memory");
  BARM();

  for (int kt = 0; kt < NTK; ++kt) {
    const int cur = kt % 3, st = (kt + 2) % 3;
    const bool dost = (kt + 2) < NTK;
    const int abase = cur * 4096, bbase = 12288 + cur * 4096;
    if (dost) {
      STAGEA(st, kt + 2, 0); STAGEA(st, kt + 2, 1);
      STAGEB(st, kt + 2, 0); STAGEB(st, kt + 2, 1);
    }
    short8 a0, a1, a2, a3, bb0, bb1, bb2, bb3;
    LDB(bb0, bbase, 0); LDB(bb1, bbase, 1); LDB(bb2, bbase, 2); LDB(bb3, bbase, 3);
    LDA(a0, abase, 0); LDA(a1, abase, 1); LDA(a2, abase, 2); LDA(a3, abase, 3);
    acc[0][0] = MFMA16(a0, bb0, acc[0][0]);
    acc[0][1] = MFMA16(a0, bb1, acc[0][1]);
    acc[0][2] = MFMA16(a0, bb2, acc[0][2]);
    acc[0][3] = MFMA16(a0, bb3, acc[0][3]);
    acc[1][0] = MFMA16(a1, bb0, acc[1][0]);
    acc[1][1] = MFMA16(a1, bb1, acc[1][1]);
    acc[1][2] = MFMA16(a1, bb2, acc[1][2]);
    acc[1][3] = MFMA16(a1, bb3, acc[1][3]);
    acc[2][0] = MFMA16(a2, bb0, acc[2][0]);
    acc[2][1] = MFMA16(a2, bb1, acc[2][1]);
    acc[2][2] = MFMA16(a2, bb2, acc[2][2]);
    acc[2][3] = MFMA16(a2, bb3, acc[2][3]);
    acc[3][0] = MFMA16(a3, bb0, acc[3][0]);
    acc[3][1] = MFMA16(a3, bb1, acc[3][1]);
    acc[3][2] = MFMA16(a3, bb2, acc[3][2]);
    acc[3][3] = MFMA16(a3, bb3, acc[3][3]);
    if (dost)                asm volatile("s_waitcnt vmcnt(4)" ::: "memory");
    else if (kt == NTK - 2)  asm volatile("s_waitcnt vmcnt(0)" ::: "memory");
    asm volatile("s_waitcnt lgkmcnt(0)" ::: "memory");   // race fix: reads drained pre-barrier
    BARM();
  }

  float bias[4];
#pragma unroll
  for (int nj = 0; nj < 4; ++nj) {
    int cn = n0 + wc * 64 + nj * 16 + lrow;
    bias[nj] = (cn < N) ? b0[cn] : 0.f;
  }
#pragma unroll
  for (int mi = 0; mi < 4; ++mi)
#pragma unroll
    for (int r = 0; r < 4; ++r) {
      int m = m0 + wr * 64 + mi * 16 + lg * 4 + r;
      if (m >= MROWS) continue;
#pragma unroll
      for (int nj = 0; nj < 4; ++nj) {
        int cn = n0 + wc * 64 + nj * 16 + lrow;
        if (cn >= N) continue;
        float v = acc[mi][nj][r] + bias[nj];
        if (OUTF32) ((float*)Cout)[(long)m * N + cn] = v;
        else        ((short*)Cout)[(long)m * N + cn] = f2bf(v);
      }
    }
#undef STAGEA
#undef STAGEB
#undef LDA
#undef LDB
#undef MFMA16
}

// ---------------- fused: fragpack(+K rotary) blocks 0..3167  |  Q-rotary blocks 3168+ ----------
// Independent regions of QKV: rotary writes Q cols [0,1152); fragpack reads K/V cols [1152,3456).
__global__ __launch_bounds__(256) void rotpack(short* __restrict__ QKV,
                                               short* __restrict__ Kf,
                                               short* __restrict__ Vf,
                                               const int* __restrict__ rowsp,
                                               const int* __restrict__ colsp) {
  __shared__ short L[64 * 96];
  const int tid = threadIdx.x;
  const int cols = colsp[0], rws = rowsp[0];
  const int off = (SEQ != rws * cols) ? 1 : 0;

  if (blockIdx.x < 3168) {
    // ---------- fragpack branch (+K rotary fused) ----------
    const int t = blockIdx.x % 33, bh = blockIdx.x / 33;
    const int b = bh / NH, h = bh % NH;
#pragma unroll
    for (int i = 0; i < 3; ++i) {
      int cc = i * 256 + tid;
      int kv = cc / 384;
      int rm = cc % 384;
      int r = rm / 12, m = rm % 12;
      int s = t * 32 + r; if (s > SEQ - 1) s = SEQ - 1;
      const short* src = QKV + (long)(b * SEQ + s) * N_QKV + (kv ? 2 * HDIM : HDIM) + h * DH + m * 8;
      *(short8*)&L[cc * 8] = *(const short8*)src;
    }
    __syncthreads();
#pragma unroll
    for (int i = 0; i < 4; ++i) {
      int idx2 = i * 256 + tid;      // 1024 = 32 rows x 32 triplets
      int r = idx2 >> 5, j = idx2 & 31;
      int s = t * 32 + r; if (s > SEQ - 1) s = SEQ - 1;
      int gid = s - off; if (gid < 0) gid = 0;
      float invf = exp2f((float)(3 * j) * (-13.287712379549449f / 192.0f));
      float st, ct, sp, cp;
      __sincosf((float)(gid / cols) * invf, &st, &ct);
      __sincosf((float)(gid % cols) * invf, &sp, &cp);
      short* pp = &L[r * 96 + 3 * j];
      float x0 = bf2f(pp[0]), x1 = bf2f(pp[1]), x2 = bf2f(pp[2]);
      pp[0] = f2bf( cp * x0 + sp * st * x1 + sp * ct * x2);
      pp[1] = f2bf( ct * x1 - st * x2);
      pp[2] = f2bf(-sp * x0 + cp * st * x1 + cp * ct * x2);
    }
    __syncthreads();
#pragma unroll
    for (int i = 0; i < 3; ++i) {
      int oc = i * 256 + tid;
      if (oc < 384) {
        int c = oc / 64, ll = oc & 63;
        int qi = ll & 31, hi = ll >> 5;
        short8 v = *(const short8*)&L[qi * 96 + c * 16 + hi * 8];
        *(short8*)(Kf + (((long)(bh * 33 + t) * 6 + c) * 64 + ll) * 8) = v;
      } else {
        int oc2 = oc - 384;
        int d = oc2 / 128, sl = (oc2 / 64) & 1, ll = oc2 & 63;
        int qi = ll & 31, hi = ll >> 5;
        short8 v;
#pragma unroll
        for (int j = 0; j < 8; ++j)
          v[j] = L[32 * 96 + (sl * 16 + hi * 8 + j) * 96 + d * 32 + qi];
        *(short8*)(Vf + ((((long)(bh * 33 + t) * 3 + d) * 2 + sl) * 64 + ll) * 8) = v;
      }
    }
  } else {
    // ---------- Q-rotary branch (vectorized short8) ----------
    int idx = (blockIdx.x - 3168) * 256 + tid;
    if (idx >= MROWS * NH * 4) return;
    const int qt = idx & 3;
    const int hm = idx >> 2;
    const int h = hm % NH, m = hm / NH;
    const int s = m % SEQ;
    int gid = s - off; if (gid < 0) gid = 0;
    const float frow = (float)(gid / cols), fcol = (float)(gid % cols);
    union { short sh[24]; short8 v[3]; } u;
    short* p = QKV + (long)m * N_QKV + h * DH + qt * 24;
    u.v[0] = *(short8*)p; u.v[1] = *(short8*)(p + 8); u.v[2] = *(short8*)(p + 16);
#pragma unroll
    for (int t = 0; t < 8; ++t) {
      int j = qt * 8 + t;
      float invf = exp2f((float)(3 * j) * (-13.287712379549449f / 192.0f));
      float st, ct, sp, cp;
      __sincosf(frow * invf, &st, &ct);
      __sincosf(fcol * invf, &sp, &cp);
      float x0 = bf2f(u.sh[3 * t]), x1 = bf2f(u.sh[3 * t + 1]), x2 = bf2f(u.sh[3 * t + 2]);
      u.sh[3 * t]     = f2bf( cp * x0 + sp * st * x1 + sp * ct * x2);
      u.sh[3 * t + 1] = f2bf( ct * x1 - st * x2);
      u.sh[3 * t + 2] = f2bf(-sp * x0 + cp * st * x1 + cp * ct * x2);
    }
    *(short8*)p = u.v[0]; *(short8*)(p + 8) = u.v[1]; *(short8*)(p + 16) = u.v[2];
  }
}

// ---------------- flash attention, swapped-operand 32x32, prepacked K/V ----------------
__global__ __launch_bounds__(128, 3) void attn_kernel(const short* __restrict__ QKV,
                                                      const short* __restrict__ Kf,
                                                      const short* __restrict__ Vf,
                                                      short* __restrict__ CTX) {
  const int tid = threadIdx.x;
  const int l = tid & 63, w = tid >> 6;
  const int qi = l & 31, hi = l >> 5;
  const int bid = blockIdx.x;
  const int xcd = bid & 7, jj = bid >> 3;
  const int bh = xcd * 12 + jj / 17;
  const int qb = jj % 17;
  const int b = bh / NH, h = bh % NH;
  const int s = qb * 64 + w * 32 + qi;
  const int sq = s > SEQ - 1 ? SEQ - 1 : s;

  const float scale = 0.1020620726159658f;  // 96^-0.5
  const short* Qr = QKV + (long)(b * SEQ + sq) * N_QKV + h * DH;
  short8 qf[6];
#pragma unroll
  for (int c = 0; c < 6; ++c) {
    short8 v = *(const short8*)(Qr + c * 16 + hi * 8);
#pragma unroll
    for (int j = 0; j < 8; ++j) v[j] = f2bf(bf2f(v[j]) * scale);
    qf[c] = v;
  }

  const short* Kb = Kf + (long)bh * 33 * 6 * 64 * 8;
  const short* Vb = Vf + (long)bh * 33 * 6 * 64 * 8;

  f32x16 ctxv[3];
#pragma unroll
  for (int d = 0; d < 3; ++d) ctxv[d] = (f32x16)(0.f);
  float m_ = -1e30f, l_ = 0.f;

  for (int t = 0; t < 33; ++t) {
    f32x16 S = (f32x16)(0.f);
#pragma unroll
    for (int c = 0; c < 6; ++c) {
      short8 kf = *(const short8*)(Kb + (((long)t * 6 + c) * 64 + l) * 8);
      S = __builtin_amdgcn_mfma_f32_32x32x16_bf16(kf, qf[c], S, 0, 0, 0);
    }
    if (t == 32) {
      S[0] = hi ? -1e30f : S[0];
#pragma unroll
      for (int r = 1; r < 16; ++r) S[r] = -1e30f;
    }
    float tm = S[0];
#pragma unroll
    for (int r = 1; r < 16; ++r) tm = fmaxf(tm, S[r]);
    tm = fmaxf(tm, __shfl_xor(tm, 32));
    if (!__all(tm - m_ <= 8.f)) {
      float mn = fmaxf(m_, tm);
      float alpha = __expf(m_ - mn);
      m_ = mn;
      l_ *= alpha;
#pragma unroll
      for (int d = 0; d < 3; ++d)
#pragma unroll
        for (int r = 0; r < 16; ++r) ctxv[d][r] *= alpha;
    }
    float ts = 0.f;
#pragma unroll
    for (int r = 0; r < 16; ++r) { float p = __expf(S[r] - m_); S[r] = p; ts += p; }
    ts += __shfl_xor(ts, 32);
    l_ += ts;

    unsigned pk_[8];
#pragma unroll
    for (int j = 0; j < 8; ++j)
      pk_[j] = (unsigned)(unsigned short)f2bf(S[2 * j]) |
               ((unsigned)(unsigned short)f2bf(S[2 * j + 1]) << 16);
    unsigned s0 = hi ? pk_[0] : pk_[2];
    unsigned s1 = hi ? pk_[1] : pk_[3];
    unsigned s2 = hi ? pk_[4] : pk_[6];
    unsigned s3 = hi ? pk_[5] : pk_[7];
    unsigned r0 = __shfl_xor(s0, 32);
    unsigned r1 = __shfl_xor(s1, 32);
    unsigned r2 = __shfl_xor(s2, 32);
    unsigned r3 = __shfl_xor(s3, 32);
    union PF { unsigned u[4]; short8 s8; } f0, f1;
    f0.u[0] = hi ? r0 : pk_[0];
    f0.u[1] = hi ? r1 : pk_[1];
    f0.u[2] = hi ? pk_[2] : r0;
    f0.u[3] = hi ? pk_[3] : r1;
    f1.u[0] = hi ? r2 : pk_[4];
    f1.u[1] = hi ? r3 : pk_[5];
    f1.u[2] = hi ? pk_[6] : r2;
    f1.u[3] = hi ? pk_[7] : r3;

#pragma unroll
    for (int d = 0; d < 3; ++d) {
      const short* Vr = Vb + (((long)t * 3 + d) * 2 * 64) * 8;
      short8 vf0 = *(const short8*)(Vr + l * 8);
      ctxv[d] = __builtin_amdgcn_mfma_f32_32x32x16_bf16(vf0, f0.s8, ctxv[d], 0, 0, 0);
      short8 vf1 = *(const short8*)(Vr + (64 + l) * 8);
      ctxv[d] = __builtin_amdgcn_mfma_f32_32x32x16_bf16(vf1, f1.s8, ctxv[d], 0, 0, 0);
    }
  }

  float invl = 1.f / l_;
  if (s <= SEQ - 1) {
    short* Cr = CTX + (long)(b * SEQ + s) * HDIM + h * DH;
#pragma unroll
    for (int d = 0; d < 3; ++d)
#pragma unroll
      for (int g = 0; g < 4; ++g) {
        short4_ o;
#pragma unroll
        for (int r = 0; r < 4; ++r) o[r] = f2bf(ctxv[d][4 * g + r] * invl);
        *(short4_*)(Cr + d * 32 + 8 * g + 4 * hi) = o;
      }
  }
}

extern "C" void kernel_launch(void* const* d_in, const int* in_sizes, int n_in,
                              void* d_out, int out_size, void* d_ws, size_t ws_size,
                              hipStream_t stream) {
  const float* hs = (const float*)d_in[0];
  const float* Wq = (const float*)d_in[1];
  const float* bq = (const float*)d_in[2];
  const float* Wk = (const float*)d_in[3];
  const float* bk = (const float*)d_in[4];
  const float* Wv = (const float*)d_in[5];
  const float* bv = (const float*)d_in[6];
  const float* Wo = (const float*)d_in[7];
  const float* bo = (const float*)d_in[8];
  const int* rows = (const int*)d_in[9];
  const int* cols = (const int*)d_in[10];
  float* out = (float*)d_out;

  char* ws = (char*)d_ws;
  short* X   = (short*)(ws);               // 8200*1152*2      = 18,892,800
  short* Wt  = (short*)(ws + 18892800);    // 3456*1152*2      =  7,962,624
  short* Wot = (short*)(ws + 26855424);    // 1152*1152*2      =  2,654,208
  short* QKV = (short*)(ws + 29509632);    // 8200*3456*2      = 56,678,400
  short* Vf  = (short*)(ws + 86188032);    // 96*33*6*64*16B   = 19,464,192
  short* CTX = (short*)(ws + 105652224);   // 8200*1152*2      = 18,892,800  (end 124,545,024)
  short* Kf  = (short*)(ws);               // 19,464,192 — reuses X+Wt region (dead after gemm<0>)

  convx<<<9225, 256, 0, stream>>>(hs, X);
  convw_t<<<dim3(18, 18, 3), 256, 0, stream>>>(Wq, Wk, Wv, Wt);
  convw_t<<<dim3(18, 18, 1), 256, 0, stream>>>(Wo, Wo, Wo, Wot);
  gemm256<0><<<462, 512, 0, stream>>>(X, Wt, bq, bk, bv, QKV, N_QKV, 33);   // 33 M x 14 N tiles
  rotpack<<<3168 + 1538, 256, 0, stream>>>(QKV, Kf, Vf, rows, cols);        // fragpack || Q-rotary
  attn_kernel<<<1632, 128, 0, stream>>>(QKV, Kf, Vf, CTX);
  gemm128<1><<<585, 256, 0, stream>>>(CTX, Wot, bo, out, HDIM, 65);         // 65 M x 9 N tiles
}

// Round 14
// 254.245 us; speedup vs baseline: 1.2586x; 1.0502x over previous
//
#include <hip/hip_runtime.h>
#include <stdint.h>

#define BATCH 8
#define SEQ   1025
#define HDIM  1152
#define NH    12
#define DH    96
#define MROWS (BATCH*SEQ)   // 8200
#define N_QKV (3*HDIM)      // 3456
#define KD    HDIM          // 1152 (K of both GEMMs)
#define NT2   18            // K-tiles of 64
#define NTK   36            // K-tiles of 32

typedef __attribute__((ext_vector_type(8))) short short8;
typedef __attribute__((ext_vector_type(4))) short short4_;
typedef __attribute__((ext_vector_type(4))) float float4_;
typedef __attribute__((ext_vector_type(16))) float f32x16;

#define AS1 __attribute__((address_space(1)))
#define AS3 __attribute__((address_space(3)))
#define BARM() do { asm volatile("" ::: "memory"); __builtin_amdgcn_s_barrier(); asm volatile("" ::: "memory"); } while (0)
#define LGKM0() do { asm volatile("s_waitcnt lgkmcnt(0)" ::: "memory"); __builtin_amdgcn_sched_barrier(0); } while (0)

__device__ inline float bf2f(short s) {
  union { unsigned u; float f; } x; x.u = ((unsigned)(unsigned short)s) << 16; return x.f;
}
__device__ inline short f2bf(float f) {
  union { float f; unsigned u; } x; x.f = f;
  unsigned r = (x.u + 0x7fffu + ((x.u >> 16) & 1u)) >> 16;
  return (short)r;
}

// ---------------- merged converts: convx (blocks 0..9224) | Wqkv^T (9225..10196) | Wo^T (10197..10520) ----
__global__ __launch_bounds__(256) void convall(const float* __restrict__ hs, short* __restrict__ X,
                                               const float* __restrict__ Wq, const float* __restrict__ Wk,
                                               const float* __restrict__ Wv, short* __restrict__ Wt,
                                               const float* __restrict__ Wo, short* __restrict__ Wot) {
  __shared__ float T[64][65];
  const int tid = threadIdx.x;
  const int bid = blockIdx.x;
  if (bid < 9225) {
    int i = bid * 256 + tid;  // exactly 2361600 threads
    float4_ v = ((const float4_*)hs)[i];
    short4_ o;
    o[0] = f2bf(v[0]); o[1] = f2bf(v[1]); o[2] = f2bf(v[2]); o[3] = f2bf(v[3]);
    ((short4_*)X)[i] = o;
    return;
  }
  // weight transpose branches
  const float* W; short* dstbase; int rem;
  if (bid < 10197) {
    int idx = bid - 9225;           // 972 = 3 * 324
    int z = idx / 324; rem = idx % 324;
    W = z == 0 ? Wq : (z == 1 ? Wk : Wv);
    dstbase = Wt + (long)z * HDIM * KD;
  } else {
    rem = bid - 10197;              // 324
    W = Wo; dstbase = Wot;
  }
  const int n0 = (rem % 18) * 64, k0 = (rem / 18) * 64;
  const int r = tid >> 2, cq = (tid & 3) * 16;
#pragma unroll
  for (int u = 0; u < 4; ++u) {
    float4_ v = *(const float4_*)&W[(long)(k0 + r) * HDIM + n0 + cq + u * 4];
    T[r][cq + u * 4 + 0] = v[0]; T[r][cq + u * 4 + 1] = v[1];
    T[r][cq + u * 4 + 2] = v[2]; T[r][cq + u * 4 + 3] = v[3];
  }
  __syncthreads();
  const int n = tid >> 2, kq = (tid & 3) * 16;
  short out[16];
#pragma unroll
  for (int u = 0; u < 16; ++u) out[u] = f2bf(T[kq + u][n]);
  short* dst = dstbase + (long)(n0 + n) * KD + k0 + kq;
  *(short8*)dst = *(short8*)&out[0];
  *(short8*)(dst + 8) = *(short8*)&out[8];
}

// ---------------- GEMM 256x256 (round-11 best, verified): 8-wave, BK=64, 4-phase ----------------
template<int OUTF32>
__global__ __launch_bounds__(512, 2) void gemm256(
    const short* __restrict__ A, const short* __restrict__ Bt,
    const float* __restrict__ b0, const float* __restrict__ b1, const float* __restrict__ b2,
    void* __restrict__ Cout, const int N, const int MT) {
  __shared__ alignas(16) short Lds[65536];  // 128KB
  const int tid = threadIdx.x;
  const int l = tid & 63, w = tid >> 6;
  const int lrow = l & 15, lg = l >> 4;
  const int wr = w >> 2, wc = w & 3;

  // bijective XCD swizzle (m204)
  const int nwg = gridDim.x;
  const int qq = nwg >> 3, r8 = nwg & 7;
  const int xcd = blockIdx.x & 7, loc = blockIdx.x >> 3;
  const int wg = (xcd < r8 ? xcd * (qq + 1) : r8 * (qq + 1) + (xcd - r8) * qq) + loc;
  const int mt = wg % MT, nt = wg / MT;
  const int m0 = mt * 256, n0 = nt * 256;

  // staging sources (inverse swizzle, round-6 verified: 0 conflicts)
  const short* asrc[2]; const short* bsrc[2];
#pragma unroll
  for (int i = 0; i < 2; ++i) {
    int p = i * 512 + tid;
    int wl = (p & 7) ^ ((p >> 3) & 7);
    int row = ((p >> 3) << 1) | (wl >> 2);
    int kc = (wl & 3) * 8;
    int ra = m0 + row; if (ra > MROWS - 1) ra = MROWS - 1;
    int rb = n0 + row; if (rb > N - 1) rb = N - 1;
    asrc[i] = A + (long)ra * KD + kc;
    bsrc[i] = Bt + (long)rb * KD + kc;
  }

#define STAGEA(sb, kh, kt_, i) \
  __builtin_amdgcn_global_load_lds((const AS1 void*)(asrc[i] + (kt_) * 64 + (kh) * 32), \
      (AS3 void*)(&Lds[(sb) * 16384 + (kh) * 8192 + (i * 512 + tid) * 8]), 16, 0, 0)
#define STAGEB(sb, kh, kt_, i) \
  __builtin_amdgcn_global_load_lds((const AS1 void*)(bsrc[i] + (kt_) * 64 + (kh) * 32), \
      (AS3 void*)(&Lds[32768 + (sb) * 16384 + (kh) * 8192 + (i * 512 + tid) * 8]), 16, 0, 0)
#define LDA(dst, base, mi) { const int row_ = wr * 128 + (mi) * 16 + lrow; \
  dst = *(const short8*)&Lds[(base) + ((row_ >> 1) << 6) + \
      (((((row_ & 1) << 2) + lg) ^ ((row_ >> 1) & 7)) << 3)]; }
#define LDB(dst, base, nj) { const int row_ = wc * 64 + (nj) * 16 + lrow; \
  dst = *(const short8*)&Lds[(base) + ((row_ >> 1) << 6) + \
      (((((row_ & 1) << 2) + lg) ^ ((row_ >> 1) & 7)) << 3)]; }
#define MFMA16(a, b, c) __builtin_amdgcn_mfma_f32_16x16x32_bf16(a, b, c, 0, 0, 0)
#define MF16(mb, A0, A1, A2, A3) \
  acc[(mb)+0][0] = MFMA16(A0, bf0, acc[(mb)+0][0]); \
  acc[(mb)+0][1] = MFMA16(A0, bf1, acc[(mb)+0][1]); \
  acc[(mb)+0][2] = MFMA16(A0, bf2, acc[(mb)+0][2]); \
  acc[(mb)+0][3] = MFMA16(A0, bf3, acc[(mb)+0][3]); \
  acc[(mb)+1][0] = MFMA16(A1, bf0, acc[(mb)+1][0]); \
  acc[(mb)+1][1] = MFMA16(A1, bf1, acc[(mb)+1][1]); \
  acc[(mb)+1][2] = MFMA16(A1, bf2, acc[(mb)+1][2]); \
  acc[(mb)+1][3] = MFMA16(A1, bf3, acc[(mb)+1][3]); \
  acc[(mb)+2][0] = MFMA16(A2, bf0, acc[(mb)+2][0]); \
  acc[(mb)+2][1] = MFMA16(A2, bf1, acc[(mb)+2][1]); \
  acc[(mb)+2][2] = MFMA16(A2, bf2, acc[(mb)+2][2]); \
  acc[(mb)+2][3] = MFMA16(A2, bf3, acc[(mb)+2][3]); \
  acc[(mb)+3][0] = MFMA16(A3, bf0, acc[(mb)+3][0]); \
  acc[(mb)+3][1] = MFMA16(A3, bf1, acc[(mb)+3][1]); \
  acc[(mb)+3][2] = MFMA16(A3, bf2, acc[(mb)+3][2]); \
  acc[(mb)+3][3] = MFMA16(A3, bf3, acc[(mb)+3][3]);

  float4_ acc[8][4];
#pragma unroll
  for (int mi = 0; mi < 8; ++mi)
#pragma unroll
    for (int nj = 0; nj < 4; ++nj) acc[mi][nj] = (float4_)(0.f);

  // prologue: stage tile 0 in FIFO order A-kh0, B-kh0, A-kh1, B-kh1 (8 loads)
  STAGEA(0, 0, 0, 0); STAGEA(0, 0, 0, 1);
  STAGEB(0, 0, 0, 0); STAGEB(0, 0, 0, 1);
  STAGEA(0, 1, 0, 0); STAGEA(0, 1, 0, 1);
  STAGEB(0, 1, 0, 0); STAGEB(0, 1, 0, 1);
  asm volatile("s_waitcnt vmcnt(4)" ::: "memory");   // tile-0 kh0 landed (oldest 4)
  BARM();

  for (int kt = 0; kt < NT2; ++kt) {
    const int cb = kt & 1, sb = (kt + 1) & 1;
    const bool dost = (kt + 1) < NT2;
    const int aK0 = cb * 16384, aK1 = aK0 + 8192;
    const int bK0 = 32768 + cb * 16384, bK1 = bK0 + 8192;
    short8 af0, af1, af2, af3, bf0, bf1, bf2, bf3;

    // ---- phase 1 (kh0, mh0): 12 ds_reads; stage A-kh0(kt+1) ----
    LDB(bf0, bK0, 0); LDB(bf1, bK0, 1); LDB(bf2, bK0, 2); LDB(bf3, bK0, 3);
    LDA(af0, aK0, 0); LDA(af1, aK0, 1); LDA(af2, aK0, 2); LDA(af3, aK0, 3);
    if (dost) { STAGEA(sb, 0, kt + 1, 0); STAGEA(sb, 0, kt + 1, 1); }
    BARM();
    LGKM0();
    __builtin_amdgcn_s_setprio(1);
    MF16(0, af0, af1, af2, af3);
    __builtin_amdgcn_s_setprio(0);
    BARM();
    // ---- phase 2 (kh0, mh1): 4 ds_reads; stage B-kh0(kt+1); mid counted vmcnt ----
    LDA(af0, aK0, 4); LDA(af1, aK0, 5); LDA(af2, aK0, 6); LDA(af3, aK0, 7);
    if (dost) { STAGEB(sb, 0, kt + 1, 0); STAGEB(sb, 0, kt + 1, 1); }
    BARM();
    LGKM0();
    __builtin_amdgcn_s_setprio(1);
    MF16(4, af0, af1, af2, af3);
    __builtin_amdgcn_s_setprio(0);
    if (dost) asm volatile("s_waitcnt vmcnt(4)" ::: "memory");  // kt's kh1 landed
    else      asm volatile("s_waitcnt vmcnt(0)" ::: "memory");  // tail drain
    BARM();
    // ---- phase 3 (kh1, mh0): 12 ds_reads; stage A-kh1(kt+1) ----
    LDB(bf0, bK1, 0); LDB(bf1, bK1, 1); LDB(bf2, bK1, 2); LDB(bf3, bK1, 3);
    LDA(af0, aK1, 0); LDA(af1, aK1, 1); LDA(af2, aK1, 2); LDA(af3, aK1, 3);
    if (dost) { STAGEA(sb, 1, kt + 1, 0); STAGEA(sb, 1, kt + 1, 1); }
    BARM();
    LGKM0();
    __builtin_amdgcn_s_setprio(1);
    MF16(0, af0, af1, af2, af3);
    __builtin_amdgcn_s_setprio(0);
    BARM();
    // ---- phase 4 (kh1, mh1): 4 ds_reads; stage B-kh1(kt+1); boundary counted vmcnt ----
    LDA(af0, aK1, 4); LDA(af1, aK1, 5); LDA(af2, aK1, 6); LDA(af3, aK1, 7);
    if (dost) { STAGEB(sb, 1, kt + 1, 0); STAGEB(sb, 1, kt + 1, 1); }
    BARM();
    LGKM0();
    __builtin_amdgcn_s_setprio(1);
    MF16(4, af0, af1, af2, af3);
    __builtin_amdgcn_s_setprio(0);
    if (dost) asm volatile("s_waitcnt vmcnt(4)" ::: "memory");  // (kt+1)'s kh0 landed
    BARM();
  }

  // epilogue: 16x16 C layout row = lg*4 + r, col = lrow
  float bias[4];
#pragma unroll
  for (int nj = 0; nj < 4; ++nj) {
    int cn = n0 + wc * 64 + nj * 16 + lrow;
    float bv_ = 0.f;
    if (cn < N) bv_ = (N == HDIM) ? b0[cn]
                                  : (cn < HDIM ? b0[cn] : (cn < 2 * HDIM ? b1[cn - HDIM] : b2[cn - 2 * HDIM]));
    bias[nj] = bv_;
  }
#pragma unroll
  for (int mi = 0; mi < 8; ++mi)
#pragma unroll
    for (int r = 0; r < 4; ++r) {
      int m = m0 + wr * 128 + mi * 16 + lg * 4 + r;
      if (m >= MROWS) continue;
#pragma unroll
      for (int nj = 0; nj < 4; ++nj) {
        int cn = n0 + wc * 64 + nj * 16 + lrow;
        if (cn >= N) continue;
        float v = acc[mi][nj][r] + bias[nj];
        if (OUTF32) ((float*)Cout)[(long)m * N + cn] = v;
        else        ((short*)Cout)[(long)m * N + cn] = f2bf(v);
      }
    }
#undef STAGEA
#undef STAGEB
#undef LDA
#undef LDB
#undef MFMA16
#undef MF16
}

// ---------------- GEMM 128x128 (round-9 verified): 4-wave, triple-buffered BK=32, 3 blk/CU ----
template<int OUTF32>
__global__ __launch_bounds__(256, 3) void gemm128(
    const short* __restrict__ A, const short* __restrict__ Bt,
    const float* __restrict__ b0,
    void* __restrict__ Cout, const int N, const int MT) {
  __shared__ alignas(16) short Lds[24576];  // 48KB
  const int tid = threadIdx.x;
  const int l = tid & 63, w = tid >> 6;
  const int lrow = l & 15, lg = l >> 4;
  const int wr = w >> 1, wc = w & 1;

  const int nwg = gridDim.x;
  const int qq = nwg >> 3, r8 = nwg & 7;
  const int xcd = blockIdx.x & 7, loc = blockIdx.x >> 3;
  const int wg = (xcd < r8 ? xcd * (qq + 1) : r8 * (qq + 1) + (xcd - r8) * qq) + loc;
  const int mt = wg % MT, nt = wg / MT;
  const int m0 = mt * 128, n0 = nt * 128;

  const short* asrc[2]; const short* bsrc[2];
#pragma unroll
  for (int i = 0; i < 2; ++i) {
    int p = i * 256 + tid;
    int wl = (p & 7) ^ ((p >> 3) & 7);
    int row = ((p >> 3) << 1) | (wl >> 2);
    int kc = (wl & 3) * 8;
    int ra = m0 + row; if (ra > MROWS - 1) ra = MROWS - 1;
    int rb = n0 + row; if (rb > N - 1) rb = N - 1;
    asrc[i] = A + (long)ra * KD + kc;
    bsrc[i] = Bt + (long)rb * KD + kc;
  }

#define STAGEA(bi, kt_, i) \
  __builtin_amdgcn_global_load_lds((const AS1 void*)(asrc[i] + (kt_) * 32), \
      (AS3 void*)(&Lds[(bi) * 4096 + (i * 256 + tid) * 8]), 16, 0, 0)
#define STAGEB(bi, kt_, i) \
  __builtin_amdgcn_global_load_lds((const AS1 void*)(bsrc[i] + (kt_) * 32), \
      (AS3 void*)(&Lds[12288 + (bi) * 4096 + (i * 256 + tid) * 8]), 16, 0, 0)
#define LDA(dst, abase, mi) { const int row_ = wr * 64 + (mi) * 16 + lrow; \
  dst = *(const short8*)&Lds[(abase) + ((row_ >> 1) << 6) + \
      (((((row_ & 1) << 2) + lg) ^ ((row_ >> 1) & 7)) << 3)]; }
#define LDB(dst, bbase, nj) { const int row_ = wc * 64 + (nj) * 16 + lrow; \
  dst = *(const short8*)&Lds[(bbase) + ((row_ >> 1) << 6) + \
      (((((row_ & 1) << 2) + lg) ^ ((row_ >> 1) & 7)) << 3)]; }
#define MFMA16(a, b, c) __builtin_amdgcn_mfma_f32_16x16x32_bf16(a, b, c, 0, 0, 0)

  float4_ acc[4][4];
#pragma unroll
  for (int mi = 0; mi < 4; ++mi)
#pragma unroll
    for (int nj = 0; nj < 4; ++nj) acc[mi][nj] = (float4_)(0.f);

  STAGEA(0, 0, 0); STAGEA(0, 0, 1); STAGEB(0, 0, 0); STAGEB(0, 0, 1);
  STAGEA(1, 1, 0); STAGEA(1, 1, 1); STAGEB(1, 1, 0); STAGEB(1, 1, 1);
  asm volatile("s_waitcnt vmcnt(4)" ::: "memory");
  BARM();

  for (int kt = 0; kt < NTK; ++kt) {
    const int cur = kt % 3, st = (kt + 2) % 3;
    const bool dost = (kt + 2) < NTK;
    const int abase = cur * 4096, bbase = 12288 + cur * 4096;
    if (dost) {
      STAGEA(st, kt + 2, 0); STAGEA(st, kt + 2, 1);
      STAGEB(st, kt + 2, 0); STAGEB(st, kt + 2, 1);
    }
    short8 a0, a1, a2, a3, bb0, bb1, bb2, bb3;
    LDB(bb0, bbase, 0); LDB(bb1, bbase, 1); LDB(bb2, bbase, 2); LDB(bb3, bbase, 3);
    LDA(a0, abase, 0); LDA(a1, abase, 1); LDA(a2, abase, 2); LDA(a3, abase, 3);
    acc[0][0] = MFMA16(a0, bb0, acc[0][0]);
    acc[0][1] = MFMA16(a0, bb1, acc[0][1]);
    acc[0][2] = MFMA16(a0, bb2, acc[0][2]);
    acc[0][3] = MFMA16(a0, bb3, acc[0][3]);
    acc[1][0] = MFMA16(a1, bb0, acc[1][0]);
    acc[1][1] = MFMA16(a1, bb1, acc[1][1]);
    acc[1][2] = MFMA16(a1, bb2, acc[1][2]);
    acc[1][3] = MFMA16(a1, bb3, acc[1][3]);
    acc[2][0] = MFMA16(a2, bb0, acc[2][0]);
    acc[2][1] = MFMA16(a2, bb1, acc[2][1]);
    acc[2][2] = MFMA16(a2, bb2, acc[2][2]);
    acc[2][3] = MFMA16(a2, bb3, acc[2][3]);
    acc[3][0] = MFMA16(a3, bb0, acc[3][0]);
    acc[3][1] = MFMA16(a3, bb1, acc[3][1]);
    acc[3][2] = MFMA16(a3, bb2, acc[3][2]);
    acc[3][3] = MFMA16(a3, bb3, acc[3][3]);
    if (dost)                asm volatile("s_waitcnt vmcnt(4)" ::: "memory");
    else if (kt == NTK - 2)  asm volatile("s_waitcnt vmcnt(0)" ::: "memory");
    asm volatile("s_waitcnt lgkmcnt(0)" ::: "memory");   // race fix: reads drained pre-barrier
    BARM();
  }

  float bias[4];
#pragma unroll
  for (int nj = 0; nj < 4; ++nj) {
    int cn = n0 + wc * 64 + nj * 16 + lrow;
    bias[nj] = (cn < N) ? b0[cn] : 0.f;
  }
#pragma unroll
  for (int mi = 0; mi < 4; ++mi)
#pragma unroll
    for (int r = 0; r < 4; ++r) {
      int m = m0 + wr * 64 + mi * 16 + lg * 4 + r;
      if (m >= MROWS) continue;
#pragma unroll
      for (int nj = 0; nj < 4; ++nj) {
        int cn = n0 + wc * 64 + nj * 16 + lrow;
        if (cn >= N) continue;
        float v = acc[mi][nj][r] + bias[nj];
        if (OUTF32) ((float*)Cout)[(long)m * N + cn] = v;
        else        ((short*)Cout)[(long)m * N + cn] = f2bf(v);
      }
    }
#undef STAGEA
#undef STAGEB
#undef LDA
#undef LDB
#undef MFMA16
}

// ---------------- fused: fragpack(+K rotary) blocks 0..3167  |  Q-rotary blocks 3168+ ----------
__global__ __launch_bounds__(256) void rotpack(short* __restrict__ QKV,
                                               short* __restrict__ Kf,
                                               short* __restrict__ Vf,
                                               const int* __restrict__ rowsp,
                                               const int* __restrict__ colsp) {
  __shared__ short L[64 * 96];
  const int tid = threadIdx.x;
  const int cols = colsp[0], rws = rowsp[0];
  const int off = (SEQ != rws * cols) ? 1 : 0;

  if (blockIdx.x < 3168) {
    const int t = blockIdx.x % 33, bh = blockIdx.x / 33;
    const int b = bh / NH, h = bh % NH;
#pragma unroll
    for (int i = 0; i < 3; ++i) {
      int cc = i * 256 + tid;
      int kv = cc / 384;
      int rm = cc % 384;
      int r = rm / 12, m = rm % 12;
      int s = t * 32 + r; if (s > SEQ - 1) s = SEQ - 1;
      const short* src = QKV + (long)(b * SEQ + s) * N_QKV + (kv ? 2 * HDIM : HDIM) + h * DH + m * 8;
      *(short8*)&L[cc * 8] = *(const short8*)src;
    }
    __syncthreads();
#pragma unroll
    for (int i = 0; i < 4; ++i) {
      int idx2 = i * 256 + tid;      // 1024 = 32 rows x 32 triplets
      int r = idx2 >> 5, j = idx2 & 31;
      int s = t * 32 + r; if (s > SEQ - 1) s = SEQ - 1;
      int gid = s - off; if (gid < 0) gid = 0;
      float invf = exp2f((float)(3 * j) * (-13.287712379549449f / 192.0f));
      float st, ct, sp, cp;
      __sincosf((float)(gid / cols) * invf, &st, &ct);
      __sincosf((float)(gid % cols) * invf, &sp, &cp);
      short* pp = &L[r * 96 + 3 * j];
      float x0 = bf2f(pp[0]), x1 = bf2f(pp[1]), x2 = bf2f(pp[2]);
      pp[0] = f2bf( cp * x0 + sp * st * x1 + sp * ct * x2);
      pp[1] = f2bf( ct * x1 - st * x2);
      pp[2] = f2bf(-sp * x0 + cp * st * x1 + cp * ct * x2);
    }
    __syncthreads();
#pragma unroll
    for (int i = 0; i < 3; ++i) {
      int oc = i * 256 + tid;
      if (oc < 384) {
        int c = oc / 64, ll = oc & 63;
        int qi = ll & 31, hi = ll >> 5;
        short8 v = *(const short8*)&L[qi * 96 + c * 16 + hi * 8];
        *(short8*)(Kf + (((long)(bh * 33 + t) * 6 + c) * 64 + ll) * 8) = v;
      } else {
        int oc2 = oc - 384;
        int d = oc2 / 128, sl = (oc2 / 64) & 1, ll = oc2 & 63;
        int qi = ll & 31, hi = ll >> 5;
        short8 v;
#pragma unroll
        for (int j = 0; j < 8; ++j)
          v[j] = L[32 * 96 + (sl * 16 + hi * 8 + j) * 96 + d * 32 + qi];
        *(short8*)(Vf + ((((long)(bh * 33 + t) * 3 + d) * 2 + sl) * 64 + ll) * 8) = v;
      }
    }
  } else {
    int idx = (blockIdx.x - 3168) * 256 + tid;
    if (idx >= MROWS * NH * 4) return;
    const int qt = idx & 3;
    const int hm = idx >> 2;
    const int h = hm % NH, m = hm / NH;
    const int s = m % SEQ;
    int gid = s - off; if (gid < 0) gid = 0;
    const float frow = (float)(gid / cols), fcol = (float)(gid % cols);
    union { short sh[24]; short8 v[3]; } u;
    short* p = QKV + (long)m * N_QKV + h * DH + qt * 24;
    u.v[0] = *(short8*)p; u.v[1] = *(short8*)(p + 8); u.v[2] = *(short8*)(p + 16);
#pragma unroll
    for (int t = 0; t < 8; ++t) {
      int j = qt * 8 + t;
      float invf = exp2f((float)(3 * j) * (-13.287712379549449f / 192.0f));
      float st, ct, sp, cp;
      __sincosf(frow * invf, &st, &ct);
      __sincosf(fcol * invf, &sp, &cp);
      float x0 = bf2f(u.sh[3 * t]), x1 = bf2f(u.sh[3 * t + 1]), x2 = bf2f(u.sh[3 * t + 2]);
      u.sh[3 * t]     = f2bf( cp * x0 + sp * st * x1 + sp * ct * x2);
      u.sh[3 * t + 1] = f2bf( ct * x1 - st * x2);
      u.sh[3 * t + 2] = f2bf(-sp * x0 + cp * st * x1 + cp * ct * x2);
    }
    *(short8*)p = u.v[0]; *(short8*)(p + 8) = u.v[1]; *(short8*)(p + 16) = u.v[2];
  }
}

// ---------------- flash attention, swapped-operand 32x32, prepacked K/V ----------------
// 4-wave blocks (128 q-rows each): halves the independent K/V L2 stream readers
// (9 q-blocks per (b,h) instead of 17; co-resident waves hit L1 on the same tile).
// T5 setprio around MFMA clusters (m191: +4-7% attn, within-probe).
__global__ __launch_bounds__(256, 4) void attn_kernel(const short* __restrict__ QKV,
                                                      const short* __restrict__ Kf,
                                                      const short* __restrict__ Vf,
                                                      short* __restrict__ CTX) {
  const int tid = threadIdx.x;
  const int l = tid & 63, w = tid >> 6;           // w in [0,4)
  const int qi = l & 31, hi = l >> 5;
  // bijective XCD swizzle: 864 = 8 xcd * (12 bh * 9 qb)
  const int bid = blockIdx.x;
  const int xcd = bid & 7, jj = bid >> 3;
  const int bh = xcd * 12 + jj / 9;
  const int qb = jj % 9;
  const int b = bh / NH, h = bh % NH;
  const int s = qb * 128 + w * 32 + qi;
  const int sq = s > SEQ - 1 ? SEQ - 1 : s;

  const float scale = 0.1020620726159658f;  // 96^-0.5
  const short* Qr = QKV + (long)(b * SEQ + sq) * N_QKV + h * DH;
  short8 qf[6];
#pragma unroll
  for (int c = 0; c < 6; ++c) {
    short8 v = *(const short8*)(Qr + c * 16 + hi * 8);
#pragma unroll
    for (int j = 0; j < 8; ++j) v[j] = f2bf(bf2f(v[j]) * scale);
    qf[c] = v;
  }

  const short* Kb = Kf + (long)bh * 33 * 6 * 64 * 8;
  const short* Vb = Vf + (long)bh * 33 * 6 * 64 * 8;

  f32x16 ctxv[3];
#pragma unroll
  for (int d = 0; d < 3; ++d) ctxv[d] = (f32x16)(0.f);
  float m_ = -1e30f, l_ = 0.f;

  for (int t = 0; t < 33; ++t) {
    f32x16 S = (f32x16)(0.f);
    __builtin_amdgcn_s_setprio(1);
#pragma unroll
    for (int c = 0; c < 6; ++c) {
      short8 kf = *(const short8*)(Kb + (((long)t * 6 + c) * 64 + l) * 8);
      S = __builtin_amdgcn_mfma_f32_32x32x16_bf16(kf, qf[c], S, 0, 0, 0);
    }
    __builtin_amdgcn_s_setprio(0);
    if (t == 32) {  // keys 1024..1055: only key 1024 (reg0, hi=0) valid
      S[0] = hi ? -1e30f : S[0];
#pragma unroll
      for (int r = 1; r < 16; ++r) S[r] = -1e30f;
    }
    float tm = S[0];
#pragma unroll
    for (int r = 1; r < 16; ++r) tm = fmaxf(tm, S[r]);
    tm = fmaxf(tm, __shfl_xor(tm, 32));
    if (!__all(tm - m_ <= 8.f)) {
      float mn = fmaxf(m_, tm);
      float alpha = __expf(m_ - mn);
      m_ = mn;
      l_ *= alpha;
#pragma unroll
      for (int d = 0; d < 3; ++d)
#pragma unroll
        for (int r = 0; r < 16; ++r) ctxv[d][r] *= alpha;
    }
    float ts = 0.f;
#pragma unroll
    for (int r = 0; r < 16; ++r) { float p = __expf(S[r] - m_); S[r] = p; ts += p; }
    ts += __shfl_xor(ts, 32);
    l_ += ts;

    unsigned pk_[8];
#pragma unroll
    for (int j = 0; j < 8; ++j)
      pk_[j] = (unsigned)(unsigned short)f2bf(S[2 * j]) |
               ((unsigned)(unsigned short)f2bf(S[2 * j + 1]) << 16);
    unsigned s0 = hi ? pk_[0] : pk_[2];
    unsigned s1 = hi ? pk_[1] : pk_[3];
    unsigned s2 = hi ? pk_[4] : pk_[6];
    unsigned s3 = hi ? pk_[5] : pk_[7];
    unsigned r0 = __shfl_xor(s0, 32);
    unsigned r1 = __shfl_xor(s1, 32);
    unsigned r2 = __shfl_xor(s2, 32);
    unsigned r3 = __shfl_xor(s3, 32);
    union PF { unsigned u[4]; short8 s8; } f0, f1;
    f0.u[0] = hi ? r0 : pk_[0];
    f0.u[1] = hi ? r1 : pk_[1];
    f0.u[2] = hi ? pk_[2] : r0;
    f0.u[3] = hi ? pk_[3] : r1;
    f1.u[0] = hi ? r2 : pk_[4];
    f1.u[1] = hi ? r3 : pk_[5];
    f1.u[2] = hi ? pk_[6] : r2;
    f1.u[3] = hi ? pk_[7] : r3;

    __builtin_amdgcn_s_setprio(1);
#pragma unroll
    for (int d = 0; d < 3; ++d) {
      const short* Vr = Vb + (((long)t * 3 + d) * 2 * 64) * 8;
      short8 vf0 = *(const short8*)(Vr + l * 8);
      ctxv[d] = __builtin_amdgcn_mfma_f32_32x32x16_bf16(vf0, f0.s8, ctxv[d], 0, 0, 0);
      short8 vf1 = *(const short8*)(Vr + (64 + l) * 8);
      ctxv[d] = __builtin_amdgcn_mfma_f32_32x32x16_bf16(vf1, f1.s8, ctxv[d], 0, 0, 0);
    }
    __builtin_amdgcn_s_setprio(0);
  }

  float invl = 1.f / l_;
  if (s <= SEQ - 1) {
    short* Cr = CTX + (long)(b * SEQ + s) * HDIM + h * DH;
#pragma unroll
    for (int d = 0; d < 3; ++d)
#pragma unroll
      for (int g = 0; g < 4; ++g) {
        short4_ o;
#pragma unroll
        for (int r = 0; r < 4; ++r) o[r] = f2bf(ctxv[d][4 * g + r] * invl);
        *(short4_*)(Cr + d * 32 + 8 * g + 4 * hi) = o;
      }
  }
}

extern "C" void kernel_launch(void* const* d_in, const int* in_sizes, int n_in,
                              void* d_out, int out_size, void* d_ws, size_t ws_size,
                              hipStream_t stream) {
  const float* hs = (const float*)d_in[0];
  const float* Wq = (const float*)d_in[1];
  const float* bq = (const float*)d_in[2];
  const float* Wk = (const float*)d_in[3];
  const float* bk = (const float*)d_in[4];
  const float* Wv = (const float*)d_in[5];
  const float* bv = (const float*)d_in[6];
  const float* Wo = (const float*)d_in[7];
  const float* bo = (const float*)d_in[8];
  const int* rows = (const int*)d_in[9];
  const int* cols = (const int*)d_in[10];
  float* out = (float*)d_out;

  char* ws = (char*)d_ws;
  short* X   = (short*)(ws);               // 8200*1152*2      = 18,892,800
  short* Wt  = (short*)(ws + 18892800);    // 3456*1152*2      =  7,962,624
  short* Wot = (short*)(ws + 26855424);    // 1152*1152*2      =  2,654,208
  short* QKV = (short*)(ws + 29509632);    // 8200*3456*2      = 56,678,400
  short* Vf  = (short*)(ws + 86188032);    // 96*33*6*64*16B   = 19,464,192
  short* CTX = (short*)(ws + 105652224);   // 8200*1152*2      = 18,892,800  (end 124,545,024)
  short* Kf  = (short*)(ws);               // 19,464,192 — reuses X+Wt region (dead after gemm<0>)

  convall<<<10521, 256, 0, stream>>>(hs, X, Wq, Wk, Wv, Wt, Wo, Wot);
  gemm256<0><<<462, 512, 0, stream>>>(X, Wt, bq, bk, bv, QKV, N_QKV, 33);   // 33 M x 14 N tiles
  rotpack<<<3168 + 1538, 256, 0, stream>>>(QKV, Kf, Vf, rows, cols);        // fragpack || Q-rotary
  attn_kernel<<<864, 256, 0, stream>>>(QKV, Kf, Vf, CTX);
  gemm128<1><<<585, 256, 0, stream>>>(CTX, Wot, bo, out, HDIM, 65);         // 65 M x 9 N tiles
}